// Round 4
// baseline (4942.239 us; speedup 1.0000x reference)
//
#include <hip/hip_runtime.h>

typedef unsigned short ushort_t;
typedef unsigned int uint_t;
typedef __attribute__((ext_vector_type(8))) short short8;   // 8 bf16 (4 VGPR) MFMA frag
typedef __attribute__((ext_vector_type(4))) float f32x4;    // MFMA accumulator frag

#define B_    16
#define L_    4096
#define H_    256
#define N_    32
#define DIN_  257
#define DOUT_ 257
#define NL_   4
#define Q_    128
#define NC_   32                 // L_/Q_
#define BL_   (B_*L_)            // 65536
#define NH_   (N_*H_)            // 8192
#define PLANE_ 16777216          // BL_*H_
#define SSZ_  4194304            // B_*NC_*N_*H_ (elements)

__device__ __forceinline__ float bfu(ushort_t u) {
    union { uint_t i; float f; } v; v.i = ((uint_t)u) << 16; return v.f;
}
__device__ __forceinline__ ushort_t f2bf(float f) {
    union { float f; uint_t i; } v; v.f = f;
    uint_t x = v.i;
    return (ushort_t)((x + 0x7FFFu + ((x >> 16) & 1u)) >> 16);
}
__device__ __forceinline__ uint2 pack4(float a, float b, float c, float d) {
    uint2 r;
    r.x = (uint_t)f2bf(a) | ((uint_t)f2bf(b) << 16);
    r.y = (uint_t)f2bf(c) | ((uint_t)f2bf(d) << 16);
    return r;
}
// dtype-flexible external-input load: f32!=0 -> fp32, else bf16
__device__ __forceinline__ float ldi(const void* p, size_t i, int f32) {
    return f32 ? ((const float*)p)[i] : bfu(((const ushort_t*)p)[i]);
}

// async global->LDS, 16B per lane (dest = wave-uniform base + lane*16)
__device__ __forceinline__ void gl16(const ushort_t* g, ushort_t* l) {
    __builtin_amdgcn_global_load_lds(
        (const __attribute__((address_space(1))) uint_t*)g,
        (__attribute__((address_space(3))) uint_t*)l, 16, 0, 0);
}

// load 8 source weights (fp32 or bf16) as packed bf16x8 (uint4); 16B-aligned src
__device__ __forceinline__ uint4 ld8bf(const void* W, size_t eoff, int f32) {
    uint4 r;
    if (f32) {
        const float* p = (const float*)W + eoff;
        float4 a = *(const float4*)p;
        float4 b = *(const float4*)(p + 4);
        r.x = (uint_t)f2bf(a.x) | ((uint_t)f2bf(a.y) << 16);
        r.y = (uint_t)f2bf(a.z) | ((uint_t)f2bf(a.w) << 16);
        r.z = (uint_t)f2bf(b.x) | ((uint_t)f2bf(b.y) << 16);
        r.w = (uint_t)f2bf(b.z) | ((uint_t)f2bf(b.w) << 16);
    } else {
        r = *(const uint4*)((const ushort_t*)W + eoff);
    }
    return r;
}

// negate 8 packed bf16 (sign-bit flip) -> used for -xi*Wi accumulation
__device__ __forceinline__ short8 negbf(short8 v) {
    short8 r;
#pragma unroll
    for (int i = 0; i < 8; ++i) r[i] = (short)(v[i] ^ (short)0x8000);
    return r;
}

#define MFMA16(a, b, c) __builtin_amdgcn_mfma_f32_16x16x32_bf16((a), (b), (c), 0, 0, 0)

// ---------------- dtype probe --------------------------------------------
__global__ void probe_kernel(const void* __restrict__ x, int* __restrict__ flag) {
    __shared__ int cnt;
    if (threadIdx.x == 0) cnt = 0;
    __syncthreads();
    uint_t w = ((const uint_t*)x)[threadIdx.x];
    float f = bfu((ushort_t)(w & 0xFFFF));
    float a = fabsf(f);
    if (a > 1e-5f && a < 100.f) atomicAdd(&cnt, 1);
    __syncthreads();
    if (threadIdx.x == 0) *flag = (cnt > 128) ? 0 : 1;  // 0 = bf16, 1 = fp32
}

// ---------------- SSM parameter precompute -------------------------------
__global__ __launch_bounds__(256) void param_kernel(
        const void* __restrict__ log_dt, const void* __restrict__ lAr,
        const void* __restrict__ Aim, const void* __restrict__ C2,
        float* __restrict__ params, const int* __restrict__ dfl) {
    int f32 = *dfl;
    int idx = blockIdx.x * 256 + threadIdx.x;   // over NL_*2*N_*H_ = 65536
    int h  = idx & (H_ - 1);
    int n  = (idx >> 8) & (N_ - 1);
    int lb = idx >> 13;                          // layer*2+branch
    float dt = expf(ldi(log_dt, lb * H_ + h, f32));
    size_t pin = (size_t)(lb * H_ + h) * N_ + n;
    float Ar = -expf(ldi(lAr, pin, f32));
    float Ai = ldi(Aim, pin, f32);
    float Cr = ldi(C2, pin * 2, f32), Ci = ldi(C2, pin * 2 + 1, f32);
    float dr = Ar * dt, di = Ai * dt;
    float e  = expf(dr);
    float wr = e * cosf(di), wi = e * sinf(di);
    float Er = wr - 1.0f, Ei = wi;               // exp(dtA) - 1
    float inv = 1.0f / (Ar * Ar + Ai * Ai);
    float Fr = (Er * Ar + Ei * Ai) * inv;        // (exp(dtA)-1)/A
    float Fi = (Ei * Ar - Er * Ai) * inv;
    float ctr = 2.0f * (Cr * Fr - Ci * Fi);
    float cti = 2.0f * (Cr * Fi + Ci * Fr);
    float eq = expf((float)Q_ * dr);
    float ph = (float)Q_ * di;
    float wqr = eq * cosf(ph), wqi = eq * sinf(ph);
    float* pb = params + (size_t)lb * 6 * NH_;
    int o = n * H_ + h;
    pb[0 * NH_ + o] = wr;  pb[1 * NH_ + o] = wi;
    pb[2 * NH_ + o] = ctr; pb[3 * NH_ + o] = cti;
    pb[4 * NH_ + o] = wqr; pb[5 * NH_ + o] = wqi;
}

// ---------------- x repack: deinterleave cols 0..255 into bf16 planes ----
__global__ __launch_bounds__(256) void repack_x(
        const void* __restrict__ x, ushort_t* __restrict__ xre,
        ushort_t* __restrict__ xim, const int* __restrict__ dfl) {
    int f32 = *dfl;
    size_t i = ((size_t)blockIdx.x * 256 + threadIdx.x) * 4;  // over BL_*256
    int row = (int)(i >> 8);
    int k = (int)(i & 255);                                   // <= 252
    size_t src = (size_t)row * DIN_ + k;
    float re[4], im[4];
#pragma unroll
    for (int j = 0; j < 4; ++j) {
        if (f32) {
            float2 v = ((const float2*)x)[src + j];
            re[j] = v.x; im[j] = v.y;
        } else {
            uint_t v = ((const uint_t*)x)[src + j];
            re[j] = bfu((ushort_t)(v & 0xFFFF));
            im[j] = bfu((ushort_t)(v >> 16));
        }
    }
    *(uint2*)(xre + i) = pack4(re[0], re[1], re[2], re[3]);
    *(uint2*)(xim + i) = pack4(im[0], im[1], im[2], im[3]);
}

// ---------------- enc weight pack: cols 0..255 -> aligned bf16 [256][256] -
__global__ __launch_bounds__(256) void pack_encw(
        const void* __restrict__ Wr, const void* __restrict__ Wi,
        ushort_t* __restrict__ Wpr, ushort_t* __restrict__ Wpi,
        const int* __restrict__ dfl) {
    int f32 = *dfl;
    int n = blockIdx.x, k = threadIdx.x;
    Wpr[n * 256 + k] = f2bf(ldi(Wr, (size_t)n * DIN_ + k, f32));
    Wpi[n * 256 + k] = f2bf(ldi(Wi, (size_t)n * DIN_ + k, f32));
}

// ---------------- Encoder: complex GEMM (MFMA), dec_gemm structure -------
// accR = xre*Wr^T - xim*Wi^T ; accI = xre*Wi^T + xim*Wr^T  over k=0..255,
// plus the ragged k=256 column as a rank-1 complex update in the epilogue.
__global__ __launch_bounds__(256) void enc_gemm(
        const ushort_t* __restrict__ xre, const ushort_t* __restrict__ xim,
        const ushort_t* __restrict__ Wpr, const ushort_t* __restrict__ Wpi,
        const void* __restrict__ x, const void* __restrict__ eWr,
        const void* __restrict__ eWi, const void* __restrict__ br,
        const void* __restrict__ bi, ushort_t* __restrict__ xr,
        ushort_t* __restrict__ xi_, const int* __restrict__ dfl) {
    __shared__ __align__(16) ushort_t Ars[8192];  // xre tile 128x64
    __shared__ __align__(16) ushort_t Ais[8192];  // xim tile 128x64
    __shared__ __align__(16) ushort_t Brs[4096];  // Wr tile  64x64
    __shared__ __align__(16) ushort_t Bis[4096];  // Wi tile  64x64
    int f32 = *dfl;
    int m0 = blockIdx.x * 128, n0 = blockIdx.y * 64;
    int tid = threadIdx.x;
    int w = tid >> 6, l = tid & 63;
    int rb = w * 32;
    int lr = l & 15, lk = (l >> 4) << 4, lsw = (l & 7) << 4;
    int arow = tid >> 3;
    int acb  = ((tid & 7) << 4) ^ ((arow & 7) << 4);
    int brow = tid >> 2;                          // 0..63
    int bq   = (tid & 3) << 5;                    // colbyte 0/32/64/96
    int bsw  = (brow & 7) << 4;
    int wrow = n0 + brow;                         // always < 256
    f32x4 z4 = {0.f, 0.f, 0.f, 0.f};
    f32x4 aR[2][4], aI[2][4];
#pragma unroll
    for (int mi = 0; mi < 2; ++mi)
#pragma unroll
        for (int nj = 0; nj < 4; ++nj) { aR[mi][nj] = z4; aI[mi][nj] = z4; }

    for (int k0 = 0; k0 < H_; k0 += 64) {
        if (k0) __syncthreads();
        {   // A: xre and xim tiles via global_load_lds (pre-swizzled source)
            size_t so = (size_t)(m0 + arow) * H_ + k0 + (acb >> 1);
            ushort_t* dr = Ars + tid * 8;
            ushort_t* di = Ais + tid * 8;
#pragma unroll
            for (int ch = 0; ch < 4; ++ch) {
                gl16(xre + so + (size_t)ch * 32 * H_, dr + ch * 2048);
                gl16(xim + so + (size_t)ch * 32 * H_, di + ch * 2048);
            }
        }
        {   // B: packed bf16 weights, aligned uint4
            char* pr_ = (char*)Brs + brow * 128;
            char* pi_ = (char*)Bis + brow * 128;
#pragma unroll
            for (int cc = 0; cc < 2; ++cc) {
                int cb = bq + cc * 16;
                *(uint4*)(pr_ + (cb ^ bsw)) =
                    *(const uint4*)(Wpr + (size_t)wrow * H_ + k0 + (cb >> 1));
                *(uint4*)(pi_ + (cb ^ bsw)) =
                    *(const uint4*)(Wpi + (size_t)wrow * H_ + k0 + (cb >> 1));
            }
        }
        __syncthreads();
#pragma unroll
        for (int ks = 0; ks < 2; ++ks) {
            int off = (ks * 64 + lk) ^ lsw;
            short8 x0 = *(const short8*)((const char*)Ars + (rb + lr) * 128 + off);
            short8 x1 = *(const short8*)((const char*)Ars + (rb + 16 + lr) * 128 + off);
            short8 y0 = *(const short8*)((const char*)Ais + (rb + lr) * 128 + off);
            short8 y1 = *(const short8*)((const char*)Ais + (rb + 16 + lr) * 128 + off);
#pragma unroll
            for (int nj = 0; nj < 4; ++nj) {
                short8 wr_ = *(const short8*)((const char*)Brs + (nj * 16 + lr) * 128 + off);
                short8 wi_ = *(const short8*)((const char*)Bis + (nj * 16 + lr) * 128 + off);
                short8 wn = negbf(wi_);
                aR[0][nj] = MFMA16(x0, wr_, aR[0][nj]);
                aR[0][nj] = MFMA16(y0, wn,  aR[0][nj]);
                aR[1][nj] = MFMA16(x1, wr_, aR[1][nj]);
                aR[1][nj] = MFMA16(y1, wn,  aR[1][nj]);
                aI[0][nj] = MFMA16(x0, wi_, aI[0][nj]);
                aI[0][nj] = MFMA16(y0, wr_, aI[0][nj]);
                aI[1][nj] = MFMA16(x1, wi_, aI[1][nj]);
                aI[1][nj] = MFMA16(y1, wr_, aI[1][nj]);
            }
        }
    }
    // ragged k=256 column inputs (one complex pair per output row)
    float xcr[8], xci[8];
#pragma unroll
    for (int mi = 0; mi < 2; ++mi)
#pragma unroll
        for (int r = 0; r < 4; ++r) {
            int row = m0 + rb + mi * 16 + ((l >> 4) << 2) + r;
            size_t pi = (size_t)row * DIN_ + 256;
            float re, im;
            if (f32) { float2 v = ((const float2*)x)[pi]; re = v.x; im = v.y; }
            else { uint_t v = ((const uint_t*)x)[pi];
                   re = bfu((ushort_t)(v & 0xFFFF)); im = bfu((ushort_t)(v >> 16)); }
            xcr[mi * 4 + r] = re; xci[mi * 4 + r] = im;
        }
#pragma unroll
    for (int nj = 0; nj < 4; ++nj) {
        int col = n0 + nj * 16 + lr;
        float wcr = ldi(eWr, (size_t)col * DIN_ + 256, f32);
        float wci = ldi(eWi, (size_t)col * DIN_ + 256, f32);
        float bR = ldi(br, col, f32), bI = ldi(bi, col, f32);
#pragma unroll
        for (int mi = 0; mi < 2; ++mi)
#pragma unroll
            for (int r = 0; r < 4; ++r) {
                int row = m0 + rb + mi * 16 + ((l >> 4) << 2) + r;
                int q = mi * 4 + r;
                float re = aR[mi][nj][r] + xcr[q] * wcr - xci[q] * wci + bR;
                float im = aI[mi][nj][r] + xcr[q] * wci + xci[q] * wcr + bI;
                size_t off = (size_t)row * H_ + col;
                xr[off]  = f2bf(re);
                xi_[off] = f2bf(im);
            }
    }
}

// ---------------- Pass A: per-chunk local state inject (states -> bf16) ---
// 4 threads per h, 8 states each; 64-h slice per block (grid.z = 4).
// U sub-tile (128 t x 64 h = 16 KB) staged to LDS via global_load_lds.
__global__ __launch_bounds__(256) void pass_a(
        const ushort_t* __restrict__ U, const float* __restrict__ P, ushort_t* __restrict__ S) {
    __shared__ __align__(16) ushort_t Us[Q_ * 64];   // 16 KB
    int c = blockIdx.x, b = blockIdx.y, z = blockIdx.z;
    int tid = threadIdx.x;
    int hl = tid >> 2, h = z * 64 + hl;
    int nb = (tid & 3) * 8;
    const ushort_t* ub = U + (size_t)(b * L_ + c * Q_) * H_ + z * 64;
#pragma unroll
    for (int p = 0; p < 4; ++p)
        gl16(ub + (size_t)(p * 32 + (tid >> 3)) * H_ + (tid & 7) * 8,
             Us + p * 2048 + tid * 8);
    float wr[8], wi[8], sr[8], si[8];
#pragma unroll
    for (int n = 0; n < 8; ++n) {
        wr[n] = P[(nb + n) * H_ + h]; wi[n] = P[NH_ + (nb + n) * H_ + h];
        sr[n] = 0.f; si[n] = 0.f;
    }
    __syncthreads();
    float uvn = bfu(Us[hl]);
    for (int t = 0; t < Q_; ++t) {
        float uv = uvn;
        int tn = (t + 1 < Q_) ? t + 1 : t;
        uvn = bfu(Us[tn * 64 + hl]);
#pragma unroll
        for (int n = 0; n < 8; ++n) {
            float nr = fmaf(wr[n], sr[n], fmaf(-wi[n], si[n], uv));
            si[n] = fmaf(wr[n], si[n], wi[n] * sr[n]);
            sr[n] = nr;
        }
    }
    size_t o = (size_t)(b * NC_ + c) * N_ * H_ + h;
#pragma unroll
    for (int n = 0; n < 8; ++n) {
        S[o + (nb + n) * H_] = f2bf(sr[n]);
        S[o + (nb + n) * H_ + SSZ_] = f2bf(si[n]);
    }
}

// ---------------- Pass B: chunk-level carry scan (in-place -> init state) -
// 1-deep software prefetch: next chunk's loads issue before current store.
__global__ __launch_bounds__(256) void pass_b(
        const float* __restrict__ P, ushort_t* __restrict__ S) {
    int n = blockIdx.x, b = blockIdx.y, h = threadIdx.x;
    float wqr = P[4 * NH_ + n * H_ + h], wqi = P[5 * NH_ + n * H_ + h];
    float Xr = 0.f, Xi = 0.f;
    size_t idx = ((size_t)(b * NC_) * N_ + n) * H_ + h;
    float nlr = bfu(S[idx]), nli = bfu(S[idx + SSZ_]);
    for (int c = 0; c < NC_; ++c) {
        float lr = nlr, li = nli;
        if (c + 1 < NC_) {
            nlr = bfu(S[idx + NH_]);
            nli = bfu(S[idx + NH_ + SSZ_]);
        }
        S[idx] = f2bf(Xr); S[idx + SSZ_] = f2bf(Xi);   // init state for chunk c
        float nr = fmaf(wqr, Xr, fmaf(-wqi, Xi, lr));
        Xi = fmaf(wqr, Xi, fmaf(wqi, Xr, li));
        Xr = nr;
        idx += NH_;
    }
}

// ---------------- Pass C: scan w/ init + y=conv+D*u -> gelu --------------
// 4 threads per h, 8 states each; 64-h slice per block (grid.z = 4).
__global__ __launch_bounds__(256) void pass_c(
        const ushort_t* __restrict__ U, const float* __restrict__ P,
        const ushort_t* __restrict__ S, const void* __restrict__ Dp, int doff,
        ushort_t* __restrict__ G, const int* __restrict__ dfl) {
    __shared__ __align__(16) ushort_t Us[Q_ * 64];  // 16 KB
    int f32 = *dfl;
    int c = blockIdx.x, b = blockIdx.y, z = blockIdx.z;
    int tid = threadIdx.x;
    int hl = tid >> 2, h = z * 64 + hl;
    int nb = (tid & 3) * 8;
    const ushort_t* ub = U + (size_t)(b * L_ + c * Q_) * H_ + z * 64;
#pragma unroll
    for (int p = 0; p < 4; ++p)
        gl16(ub + (size_t)(p * 32 + (tid >> 3)) * H_ + (tid & 7) * 8,
             Us + p * 2048 + tid * 8);
    float wr[8], wi[8], cr[8], ci[8], sr[8], si[8];
#pragma unroll
    for (int i = 0; i < 8; ++i) {
        int o = (nb + i) * H_ + h;
        wr[i] = P[o]; wi[i] = P[NH_ + o];
        cr[i] = P[2 * NH_ + o]; ci[i] = P[3 * NH_ + o];
    }
    size_t so = (size_t)(b * NC_ + c) * N_ * H_ + h;
#pragma unroll
    for (int i = 0; i < 8; ++i) {
        sr[i] = bfu(S[so + (nb + i) * H_]);
        si[i] = bfu(S[so + (nb + i) * H_ + SSZ_]);
    }
    float Dv = ldi(Dp, (size_t)doff + h, f32);
    ushort_t* g = G + (size_t)(b * L_ + c * Q_) * H_ + h;
    __syncthreads();
    float uvn = bfu(Us[hl]);
    for (int t = 0; t < Q_; ++t) {
        float uv = uvn;
        int tn = (t + 1 < Q_) ? t + 1 : t;
        uvn = bfu(Us[tn * 64 + hl]);
        float a0 = 0.f, a1 = 0.f;
#pragma unroll
        for (int i = 0; i < 8; ++i) {
            float nr = fmaf(wr[i], sr[i], fmaf(-wi[i], si[i], uv));
            si[i] = fmaf(wr[i], si[i], wi[i] * sr[i]);
            sr[i] = nr;
            if (i & 1) a1 = fmaf(cr[i], sr[i], fmaf(-ci[i], si[i], a1));
            else       a0 = fmaf(cr[i], sr[i], fmaf(-ci[i], si[i], a0));
        }
        float acc = a0 + a1;
        acc += __shfl_xor(acc, 1, 64);           // combine 4 state-quarters
        acc += __shfl_xor(acc, 2, 64);
        float y = fmaf(Dv, uv, acc);
        float ge = 0.5f * y * (1.0f + erff(y * 0.70710678118654752f));
        if ((tid & 3) == 0) g[(size_t)t * H_] = f2bf(ge);
    }
}

// ---------------- Wout GEMM (MFMA) + bias + GLU, accumulate into z -------
// mode: 0 = store, 1 = add, 2 = sub
__global__ __launch_bounds__(256) void wout_gemm(
        const ushort_t* __restrict__ Gb, const void* __restrict__ W, size_t woff,
        const void* __restrict__ bo, int boff, ushort_t* __restrict__ Z, int mode,
        const int* __restrict__ dfl) {
    __shared__ __align__(16) ushort_t As[8192];   // 128 x 64 bf16 (swizzled)
    __shared__ __align__(16) ushort_t Bs[8192];   // 128 x 64 bf16 (swizzled)
    int f32 = *dfl;
    int m0 = blockIdx.x * 128, n0 = blockIdx.y * 64;
    int tid = threadIdx.x;
    int w = tid >> 6, l = tid & 63;
    int rb = w * 32;                              // wave's 32-row slice
    int lr = l & 15, lk = (l >> 4) << 4;          // frag row-in-16 / k-octet byte
    int lsw = (l & 7) << 4;                       // read-side swizzle
    // A-stage (global_load_lds, pre-swizzled source):
    int arow = tid >> 3;                          // 0..31 (+ch*32)
    int acb  = ((tid & 7) << 4) ^ ((arow & 7) << 4);  // logical colbyte at dest slot
    // B-stage (reg-staged, handles fp32-or-bf16 weights):
    int brow = tid >> 1;                          // 0..127
    int bhalf = (tid & 1) << 6;                   // colbyte 0 or 64
    int bsw = (brow & 7) << 4;
    int wrow = (brow < 64) ? (n0 + brow) : (192 + n0 + brow);  // a rows / g rows
    f32x4 z4 = {0.f, 0.f, 0.f, 0.f};
    f32x4 acc[2][8];
#pragma unroll
    for (int mi = 0; mi < 2; ++mi)
#pragma unroll
        for (int nj = 0; nj < 8; ++nj) acc[mi][nj] = z4;

    for (int k0 = 0; k0 < H_; k0 += 64) {
        if (k0) __syncthreads();
        {   // A: 128x64 bf16, 4 chunks of 256 lanes x 16B
            const ushort_t* src = Gb + (size_t)(m0 + arow) * H_ + k0 + (acb >> 1);
            ushort_t* dst = As + tid * 8;
#pragma unroll
            for (int ch = 0; ch < 4; ++ch)
                gl16(src + (size_t)ch * 32 * H_, dst + ch * 2048);
        }
        {   // B: W rows -> swizzled LDS (64B per thread)
            size_t wb = woff + (size_t)wrow * H_ + k0;
            char* bp = (char*)Bs + brow * 128;
#pragma unroll
            for (int cc = 0; cc < 4; ++cc) {
                int cb = bhalf + cc * 16;
                uint4 v = ld8bf(W, wb + (cb >> 1), f32);
                *(uint4*)(bp + (cb ^ bsw)) = v;
            }
        }
        __syncthreads();
#pragma unroll
        for (int ks = 0; ks < 2; ++ks) {
            int off = (ks * 64 + lk) ^ lsw;
            short8 a0 = *(const short8*)((const char*)As + (rb + lr) * 128 + off);
            short8 a1 = *(const short8*)((const char*)As + (rb + 16 + lr) * 128 + off);
#pragma unroll
            for (int nj = 0; nj < 8; ++nj) {
                short8 bv = *(const short8*)((const char*)Bs + (nj * 16 + lr) * 128 + off);
                acc[0][nj] = MFMA16(a0, bv, acc[0][nj]);
                acc[1][nj] = MFMA16(a1, bv, acc[1][nj]);
            }
        }
    }
    float ba[4], bg[4];
#pragma unroll
    for (int nj = 0; nj < 4; ++nj) {
        ba[nj] = ldi(bo, (size_t)boff + n0 + nj * 16 + lr, f32);
        bg[nj] = ldi(bo, (size_t)boff + 256 + n0 + nj * 16 + lr, f32);
    }
#pragma unroll
    for (int mi = 0; mi < 2; ++mi)
#pragma unroll
        for (int nj = 0; nj < 4; ++nj)
#pragma unroll
            for (int r = 0; r < 4; ++r) {
                float av = acc[mi][nj][r] + ba[nj];
                float gv = acc[mi][nj + 4][r] + bg[nj];
                float s = av * (1.0f / (1.0f + expf(-gv)));
                int row = m0 + rb + mi * 16 + ((l >> 4) << 2) + r;
                size_t zo = (size_t)row * H_ + n0 + nj * 16 + lr;
                if (mode == 0)      Z[zo] = f2bf(s);
                else if (mode == 1) Z[zo] = f2bf(bfu(Z[zo]) + s);
                else                Z[zo] = f2bf(bfu(Z[zo]) - s);
            }
}

// ---------------- residual + LayerNorm: one wave per row -----------------
__global__ __launch_bounds__(256) void combine_ln(
        ushort_t* __restrict__ xr, ushort_t* __restrict__ xi,
        const ushort_t* __restrict__ zr, const ushort_t* __restrict__ zi,
        const void* __restrict__ gamma, const void* __restrict__ beta, int layer,
        const int* __restrict__ dfl) {
    int f32 = *dfl;
    int tid = threadIdx.x;
    int wv = tid >> 6, l = tid & 63;
    size_t row = (size_t)blockIdx.x * 4 + wv;
    size_t base = row * H_ + l * 4;
    uint2 vr2 = *(const uint2*)(xr + base);
    uint2 vi2 = *(const uint2*)(xi + base);
    uint2 zr2 = *(const uint2*)(zr + base);
    uint2 zi2 = *(const uint2*)(zi + base);
    float vr[4], vi[4];
    vr[0] = bfu((ushort_t)(vr2.x & 0xFFFF)) + bfu((ushort_t)(zr2.x & 0xFFFF));
    vr[1] = bfu((ushort_t)(vr2.x >> 16))    + bfu((ushort_t)(zr2.x >> 16));
    vr[2] = bfu((ushort_t)(vr2.y & 0xFFFF)) + bfu((ushort_t)(zr2.y & 0xFFFF));
    vr[3] = bfu((ushort_t)(vr2.y >> 16))    + bfu((ushort_t)(zr2.y >> 16));
    vi[0] = bfu((ushort_t)(vi2.x & 0xFFFF)) + bfu((ushort_t)(zi2.x & 0xFFFF));
    vi[1] = bfu((ushort_t)(vi2.x >> 16))    + bfu((ushort_t)(zi2.x >> 16));
    vi[2] = bfu((ushort_t)(vi2.y & 0xFFFF)) + bfu((ushort_t)(zi2.y & 0xFFFF));
    vi[3] = bfu((ushort_t)(vi2.y >> 16))    + bfu((ushort_t)(zi2.y >> 16));
    float s0 = 0.f, s1 = 0.f, s2 = 0.f, s3 = 0.f;
#pragma unroll
    for (int j = 0; j < 4; ++j) {
        s0 += vr[j]; s1 += vr[j] * vr[j];
        s2 += vi[j]; s3 += vi[j] * vi[j];
    }
#pragma unroll
    for (int off = 32; off >= 1; off >>= 1) {
        s0 += __shfl_xor(s0, off, 64); s1 += __shfl_xor(s1, off, 64);
        s2 += __shfl_xor(s2, off, 64); s3 += __shfl_xor(s3, off, 64);
    }
    const float invH = 1.0f / 256.0f;
    float mur = s0 * invH, varr = s1 * invH - mur * mur;
    float mui = s2 * invH, vari = s3 * invH - mui * mui;
    float rsr = rsqrtf(varr + 1e-5f), rsi = rsqrtf(vari + 1e-5f);
    float orv[4], oiv[4];
#pragma unroll
    for (int j = 0; j < 4; ++j) {
        int hh = l * 4 + j;
        float gr  = ldi(gamma, (size_t)(layer * 2 + 0) * H_ + hh, f32);
        float br_ = ldi(beta,  (size_t)(layer * 2 + 0) * H_ + hh, f32);
        float gi  = ldi(gamma, (size_t)(layer * 2 + 1) * H_ + hh, f32);
        float bi_ = ldi(beta,  (size_t)(layer * 2 + 1) * H_ + hh, f32);
        orv[j] = (vr[j] - mur) * rsr * gr + br_;
        oiv[j] = (vi[j] - mui) * rsi * gi + bi_;
    }
    *(uint2*)(xr + base) = pack4(orv[0], orv[1], orv[2], orv[3]);
    *(uint2*)(xi + base) = pack4(oiv[0], oiv[1], oiv[2], oiv[3]);
}

// ---------------- Decoder: complex GEMM (MFMA) (BL x 256) -> 257 ---------
__global__ __launch_bounds__(256) void dec_gemm(
        const ushort_t* __restrict__ xr, const ushort_t* __restrict__ xi,
        const void* __restrict__ Wr, const void* __restrict__ Wi,
        const void* __restrict__ br, const void* __restrict__ bi,
        void* __restrict__ out, const int* __restrict__ dfl) {
    __shared__ __align__(16) ushort_t Ars[8192];  // xr tile 128x64
    __shared__ __align__(16) ushort_t Ais[8192];  // xi tile 128x64
    __shared__ __align__(16) ushort_t Brs[4096];  // Wr tile  64x64
    __shared__ __align__(16) ushort_t Bis[4096];  // Wi tile  64x64
    int f32 = *dfl;
    int m0 = blockIdx.x * 128, n0 = blockIdx.y * 64;
    int tid = threadIdx.x;
    int w = tid >> 6, l = tid & 63;
    int rb = w * 32;
    int lr = l & 15, lk = (l >> 4) << 4, lsw = (l & 7) << 4;
    int arow = tid >> 3;
    int acb  = ((tid & 7) << 4) ^ ((arow & 7) << 4);
    int brow = tid >> 2;                          // 0..63
    int bq   = (tid & 3) << 5;                    // colbyte 0/32/64/96
    int bsw  = (brow & 7) << 4;
    int wrow = n0 + brow;
    bool bvalid = wrow < DOUT_;
    uint4 zz; zz.x = zz.y = zz.z = zz.w = 0u;
    f32x4 z4 = {0.f, 0.f, 0.f, 0.f};
    f32x4 aR[2][4], aI[2][4];
#pragma unroll
    for (int mi = 0; mi < 2; ++mi)
#pragma unroll
        for (int nj = 0; nj < 4; ++nj) { aR[mi][nj] = z4; aI[mi][nj] = z4; }

    for (int k0 = 0; k0 < H_; k0 += 64) {
        if (k0) __syncthreads();
        {   // A: xr and xi tiles via global_load_lds (pre-swizzled source)
            size_t so = (size_t)(m0 + arow) * H_ + k0 + (acb >> 1);
            ushort_t* dr = Ars + tid * 8;
            ushort_t* di = Ais + tid * 8;
#pragma unroll
            for (int ch = 0; ch < 4; ++ch) {
                gl16(xr + so + (size_t)ch * 32 * H_, dr + ch * 2048);
                gl16(xi + so + (size_t)ch * 32 * H_, di + ch * 2048);
            }
        }
        {   // B: Wr/Wi rows -> swizzled LDS, zero-fill past row 256
            size_t wb = (size_t)wrow * H_ + k0 + (bq >> 1);
            char* pr_ = (char*)Brs + brow * 128;
            char* pi_ = (char*)Bis + brow * 128;
#pragma unroll
            for (int cc = 0; cc < 2; ++cc) {
                int cb = bq + cc * 16;
                uint4 vr = zz, vi = zz;
                if (bvalid) {
                    vr = ld8bf(Wr, wb + cc * 8, f32);
                    vi = ld8bf(Wi, wb + cc * 8, f32);
                }
                *(uint4*)(pr_ + (cb ^ bsw)) = vr;
                *(uint4*)(pi_ + (cb ^ bsw)) = vi;
            }
        }
        __syncthreads();
#pragma unroll
        for (int ks = 0; ks < 2; ++ks) {
            int off = (ks * 64 + lk) ^ lsw;
            short8 x0 = *(const short8*)((const char*)Ars + (rb + lr) * 128 + off);
            short8 x1 = *(const short8*)((const char*)Ars + (rb + 16 + lr) * 128 + off);
            short8 y0 = *(const short8*)((const char*)Ais + (rb + lr) * 128 + off);
            short8 y1 = *(const short8*)((const char*)Ais + (rb + 16 + lr) * 128 + off);
#pragma unroll
            for (int nj = 0; nj < 4; ++nj) {
                short8 wr_ = *(const short8*)((const char*)Brs + (nj * 16 + lr) * 128 + off);
                short8 wi_ = *(const short8*)((const char*)Bis + (nj * 16 + lr) * 128 + off);
                short8 wn = negbf(wi_);
                aR[0][nj] = MFMA16(x0, wr_, aR[0][nj]);
                aR[0][nj] = MFMA16(y0, wn,  aR[0][nj]);
                aR[1][nj] = MFMA16(x1, wr_, aR[1][nj]);
                aR[1][nj] = MFMA16(y1, wn,  aR[1][nj]);
                aI[0][nj] = MFMA16(x0, wi_, aI[0][nj]);
                aI[0][nj] = MFMA16(y0, wr_, aI[0][nj]);
                aI[1][nj] = MFMA16(x1, wi_, aI[1][nj]);
                aI[1][nj] = MFMA16(y1, wr_, aI[1][nj]);
            }
        }
    }
#pragma unroll
    for (int nj = 0; nj < 4; ++nj) {
        int col = n0 + nj * 16 + lr;
        if (col < DOUT_) {
            float bR = ldi(br, col, f32), bI = ldi(bi, col, f32);
#pragma unroll
            for (int mi = 0; mi < 2; ++mi)
#pragma unroll
                for (int r = 0; r < 4; ++r) {
                    int row = m0 + rb + mi * 16 + ((l >> 4) << 2) + r;
                    size_t pi = (size_t)row * DOUT_ + col;
                    float re = aR[mi][nj][r] + bR;
                    float im = aI[mi][nj][r] + bI;
                    if (f32) {
                        ((float2*)out)[pi] = make_float2(re, im);
                    } else {
                        ((uint_t*)out)[pi] = (uint_t)f2bf(re) | ((uint_t)f2bf(im) << 16);
                    }
                }
        }
    }
}

// -------------------------------------------------------------------------
extern "C" void kernel_launch(void* const* d_in, const int* in_sizes, int n_in,
                              void* d_out, int out_size, void* d_ws, size_t ws_size,
                              hipStream_t stream) {
    const void* x      = d_in[0];
    const void* enc_Wr = d_in[1];
    const void* enc_Wi = d_in[2];
    const void* enc_br = d_in[3];
    const void* enc_bi = d_in[4];
    const void* log_dt = d_in[5];
    const void* lAr    = d_in[6];
    const void* Aim    = d_in[7];
    const void* C2     = d_in[8];
    const void* Dp     = d_in[9];
    const void* Wout   = d_in[10];
    const void* bout   = d_in[11];
    const void* gamma  = d_in[12];
    const void* beta   = d_in[13];
    const void* dec_Wr = d_in[14];
    const void* dec_Wi = d_in[15];
    const void* dec_br = d_in[16];
    const void* dec_bi = d_in[17];

    // ws layout (~113.6 MiB):
    //   xr (32M) | xi (32M) | gb (32M) | st bf16 (16M) | flag | pr fp32 (1.5M)
    // zr/zi live in d_out (dead until dec_gemm rewrites every element last);
    // before the layer loop they double as repacked-x planes, and the head of
    // st doubles as the packed bf16 enc-weight buffer.
    ushort_t* xr = (ushort_t*)d_ws;
    ushort_t* xi = xr + (size_t)PLANE_;
    ushort_t* gb = xi + (size_t)PLANE_;
    ushort_t* st = gb + (size_t)PLANE_;
    int*      fl = (int*)(st + (size_t)2 * SSZ_);
    float*    pr = (float*)(fl + 64);            // 256-byte pad for alignment
    ushort_t* zr = (ushort_t*)d_out;
    ushort_t* zi = zr + (size_t)PLANE_;
    ushort_t* xre = zr;                          // repacked x planes (pre-loop)
    ushort_t* xim = zi;
    ushort_t* Wpr = st;                          // packed enc weights (pre-loop)
    ushort_t* Wpi = st + 65536;

    probe_kernel<<<1, 256, 0, stream>>>(x, fl);
    param_kernel<<<256, 256, 0, stream>>>(log_dt, lAr, Aim, C2, pr, fl);
    repack_x<<<16384, 256, 0, stream>>>(x, xre, xim, fl);
    pack_encw<<<256, 256, 0, stream>>>(enc_Wr, enc_Wi, Wpr, Wpi, fl);
    enc_gemm<<<dim3(BL_ / 128, H_ / 64), 256, 0, stream>>>(xre, xim, Wpr, Wpi,
            x, enc_Wr, enc_Wi, enc_br, enc_bi, xr, xi, fl);

    for (int l = 0; l < NL_; ++l) {
        // zr = sr(xr) - si(xi);  zi = sr(xi) + si(xr)
        struct App { int br; const ushort_t* U; ushort_t* Zt; int mode; };
        App apps[4] = {
            {0, xr, zr, 0},   // sr(xr) -> zr (store)
            {1, xi, zr, 2},   // si(xi) -> zr (sub)
            {0, xi, zi, 0},   // sr(xi) -> zi (store)
            {1, xr, zi, 1},   // si(xr) -> zi (add)
        };
        for (int a = 0; a < 4; ++a) {
            const float* P = pr + (size_t)(l * 2 + apps[a].br) * 6 * NH_;
            pass_a<<<dim3(NC_, B_, 4), 256, 0, stream>>>(apps[a].U, P, st);
            pass_b<<<dim3(N_, B_), 256, 0, stream>>>(P, st);
            pass_c<<<dim3(NC_, B_, 4), 256, 0, stream>>>(apps[a].U, P, st,
                    Dp, (l * 2 + apps[a].br) * H_, gb, fl);
            wout_gemm<<<dim3(BL_ / 128, H_ / 64), 256, 0, stream>>>(gb,
                    Wout, (size_t)(l * 2 + apps[a].br) * 512 * H_,
                    bout, (l * 2 + apps[a].br) * 512,
                    apps[a].Zt, apps[a].mode, fl);
        }
        combine_ln<<<BL_ / 4, 256, 0, stream>>>(xr, xi, zr, zi, gamma, beta, l, fl);
    }

    dec_gemm<<<dim3(BL_ / 128, (DOUT_ + 63) / 64), 256, 0, stream>>>(
            xr, xi, dec_Wr, dec_Wi, dec_br, dec_bi, d_out, fl);
}

// Round 5
// 4482.426 us; speedup vs baseline: 1.1026x; 1.1026x over previous
//
#include <hip/hip_runtime.h>

typedef unsigned short ushort_t;
typedef unsigned int uint_t;
typedef __attribute__((ext_vector_type(8))) short short8;   // 8 bf16 (4 VGPR) MFMA frag
typedef __attribute__((ext_vector_type(4))) float f32x4;    // MFMA accumulator frag
typedef __attribute__((ext_vector_type(2))) float f32x2;    // packed fp32 (v_pk_fma_f32)

#define B_    16
#define L_    4096
#define H_    256
#define N_    32
#define DIN_  257
#define DOUT_ 257
#define NL_   4
#define Q_    128
#define NC_   32                 // L_/Q_
#define BL_   (B_*L_)            // 65536
#define NH_   (N_*H_)            // 8192
#define PLANE_ 16777216          // BL_*H_
#define SSZ_  4194304            // B_*NC_*N_*H_ (elements)

__device__ __forceinline__ float bfu(ushort_t u) {
    union { uint_t i; float f; } v; v.i = ((uint_t)u) << 16; return v.f;
}
__device__ __forceinline__ ushort_t f2bf(float f) {
    union { float f; uint_t i; } v; v.f = f;
    uint_t x = v.i;
    return (ushort_t)((x + 0x7FFFu + ((x >> 16) & 1u)) >> 16);
}
__device__ __forceinline__ uint2 pack4(float a, float b, float c, float d) {
    uint2 r;
    r.x = (uint_t)f2bf(a) | ((uint_t)f2bf(b) << 16);
    r.y = (uint_t)f2bf(c) | ((uint_t)f2bf(d) << 16);
    return r;
}
// dtype-flexible external-input load: f32!=0 -> fp32, else bf16
__device__ __forceinline__ float ldi(const void* p, size_t i, int f32) {
    return f32 ? ((const float*)p)[i] : bfu(((const ushort_t*)p)[i]);
}

// packed fp32 fma: lowers to v_pk_fma_f32 on gfx950 (2 FMA/lane/inst)
__device__ __forceinline__ f32x2 fma2(f32x2 a, f32x2 b, f32x2 c) {
#if __has_builtin(__builtin_elementwise_fma)
    return __builtin_elementwise_fma(a, b, c);
#else
    f32x2 r; r.x = fmaf(a.x, b.x, c.x); r.y = fmaf(a.y, b.y, c.y); return r;
#endif
}

// async global->LDS, 16B per lane (dest = wave-uniform base + lane*16)
__device__ __forceinline__ void gl16(const ushort_t* g, ushort_t* l) {
    __builtin_amdgcn_global_load_lds(
        (const __attribute__((address_space(1))) uint_t*)g,
        (__attribute__((address_space(3))) uint_t*)l, 16, 0, 0);
}

// load 8 source weights (fp32 or bf16) as packed bf16x8 (uint4); 16B-aligned src
__device__ __forceinline__ uint4 ld8bf(const void* W, size_t eoff, int f32) {
    uint4 r;
    if (f32) {
        const float* p = (const float*)W + eoff;
        float4 a = *(const float4*)p;
        float4 b = *(const float4*)(p + 4);
        r.x = (uint_t)f2bf(a.x) | ((uint_t)f2bf(a.y) << 16);
        r.y = (uint_t)f2bf(a.z) | ((uint_t)f2bf(a.w) << 16);
        r.z = (uint_t)f2bf(b.x) | ((uint_t)f2bf(b.y) << 16);
        r.w = (uint_t)f2bf(b.z) | ((uint_t)f2bf(b.w) << 16);
    } else {
        r = *(const uint4*)((const ushort_t*)W + eoff);
    }
    return r;
}

// negate 8 packed bf16 (sign-bit flip) -> used for -xi*Wi accumulation
__device__ __forceinline__ short8 negbf(short8 v) {
    short8 r;
#pragma unroll
    for (int i = 0; i < 8; ++i) r[i] = (short)(v[i] ^ (short)0x8000);
    return r;
}

#define MFMA16(a, b, c) __builtin_amdgcn_mfma_f32_16x16x32_bf16((a), (b), (c), 0, 0, 0)

// ---------------- dtype probe --------------------------------------------
__global__ void probe_kernel(const void* __restrict__ x, int* __restrict__ flag) {
    __shared__ int cnt;
    if (threadIdx.x == 0) cnt = 0;
    __syncthreads();
    uint_t w = ((const uint_t*)x)[threadIdx.x];
    float f = bfu((ushort_t)(w & 0xFFFF));
    float a = fabsf(f);
    if (a > 1e-5f && a < 100.f) atomicAdd(&cnt, 1);
    __syncthreads();
    if (threadIdx.x == 0) *flag = (cnt > 128) ? 0 : 1;  // 0 = bf16, 1 = fp32
}

// ---------------- SSM parameter precompute -------------------------------
__global__ __launch_bounds__(256) void param_kernel(
        const void* __restrict__ log_dt, const void* __restrict__ lAr,
        const void* __restrict__ Aim, const void* __restrict__ C2,
        float* __restrict__ params, const int* __restrict__ dfl) {
    int f32 = *dfl;
    int idx = blockIdx.x * 256 + threadIdx.x;   // over NL_*2*N_*H_ = 65536
    int h  = idx & (H_ - 1);
    int n  = (idx >> 8) & (N_ - 1);
    int lb = idx >> 13;                          // layer*2+branch
    float dt = expf(ldi(log_dt, lb * H_ + h, f32));
    size_t pin = (size_t)(lb * H_ + h) * N_ + n;
    float Ar = -expf(ldi(lAr, pin, f32));
    float Ai = ldi(Aim, pin, f32);
    float Cr = ldi(C2, pin * 2, f32), Ci = ldi(C2, pin * 2 + 1, f32);
    float dr = Ar * dt, di = Ai * dt;
    float e  = expf(dr);
    float wr = e * cosf(di), wi = e * sinf(di);
    float Er = wr - 1.0f, Ei = wi;               // exp(dtA) - 1
    float inv = 1.0f / (Ar * Ar + Ai * Ai);
    float Fr = (Er * Ar + Ei * Ai) * inv;        // (exp(dtA)-1)/A
    float Fi = (Ei * Ar - Er * Ai) * inv;
    float ctr = 2.0f * (Cr * Fr - Ci * Fi);
    float cti = 2.0f * (Cr * Fi + Ci * Fr);
    float eq = expf((float)Q_ * dr);
    float ph = (float)Q_ * di;
    float wqr = eq * cosf(ph), wqi = eq * sinf(ph);
    float* pb = params + (size_t)lb * 6 * NH_;
    int o = n * H_ + h;
    pb[0 * NH_ + o] = wr;  pb[1 * NH_ + o] = wi;
    pb[2 * NH_ + o] = ctr; pb[3 * NH_ + o] = cti;
    pb[4 * NH_ + o] = wqr; pb[5 * NH_ + o] = wqi;
}

// ---------------- x repack: deinterleave cols 0..255 into bf16 planes ----
__global__ __launch_bounds__(256) void repack_x(
        const void* __restrict__ x, ushort_t* __restrict__ xre,
        ushort_t* __restrict__ xim, const int* __restrict__ dfl) {
    int f32 = *dfl;
    size_t i = ((size_t)blockIdx.x * 256 + threadIdx.x) * 4;  // over BL_*256
    int row = (int)(i >> 8);
    int k = (int)(i & 255);                                   // <= 252
    size_t src = (size_t)row * DIN_ + k;
    float re[4], im[4];
#pragma unroll
    for (int j = 0; j < 4; ++j) {
        if (f32) {
            float2 v = ((const float2*)x)[src + j];
            re[j] = v.x; im[j] = v.y;
        } else {
            uint_t v = ((const uint_t*)x)[src + j];
            re[j] = bfu((ushort_t)(v & 0xFFFF));
            im[j] = bfu((ushort_t)(v >> 16));
        }
    }
    *(uint2*)(xre + i) = pack4(re[0], re[1], re[2], re[3]);
    *(uint2*)(xim + i) = pack4(im[0], im[1], im[2], im[3]);
}

// ---------------- enc weight pack: cols 0..255 -> aligned bf16 [256][256] -
__global__ __launch_bounds__(256) void pack_encw(
        const void* __restrict__ Wr, const void* __restrict__ Wi,
        ushort_t* __restrict__ Wpr, ushort_t* __restrict__ Wpi,
        const int* __restrict__ dfl) {
    int f32 = *dfl;
    int n = blockIdx.x, k = threadIdx.x;
    Wpr[n * 256 + k] = f2bf(ldi(Wr, (size_t)n * DIN_ + k, f32));
    Wpi[n * 256 + k] = f2bf(ldi(Wi, (size_t)n * DIN_ + k, f32));
}

// ---------------- Encoder: complex GEMM (MFMA), dec_gemm structure -------
__global__ __launch_bounds__(256) void enc_gemm(
        const ushort_t* __restrict__ xre, const ushort_t* __restrict__ xim,
        const ushort_t* __restrict__ Wpr, const ushort_t* __restrict__ Wpi,
        const void* __restrict__ x, const void* __restrict__ eWr,
        const void* __restrict__ eWi, const void* __restrict__ br,
        const void* __restrict__ bi, ushort_t* __restrict__ xr,
        ushort_t* __restrict__ xi_, const int* __restrict__ dfl) {
    __shared__ __align__(16) ushort_t Ars[8192];  // xre tile 128x64
    __shared__ __align__(16) ushort_t Ais[8192];  // xim tile 128x64
    __shared__ __align__(16) ushort_t Brs[4096];  // Wr tile  64x64
    __shared__ __align__(16) ushort_t Bis[4096];  // Wi tile  64x64
    int f32 = *dfl;
    int m0 = blockIdx.x * 128, n0 = blockIdx.y * 64;
    int tid = threadIdx.x;
    int w = tid >> 6, l = tid & 63;
    int rb = w * 32;
    int lr = l & 15, lk = (l >> 4) << 4, lsw = (l & 7) << 4;
    int arow = tid >> 3;
    int acb  = ((tid & 7) << 4) ^ ((arow & 7) << 4);
    int brow = tid >> 2;                          // 0..63
    int bq   = (tid & 3) << 5;                    // colbyte 0/32/64/96
    int bsw  = (brow & 7) << 4;
    int wrow = n0 + brow;                         // always < 256
    f32x4 z4 = {0.f, 0.f, 0.f, 0.f};
    f32x4 aR[2][4], aI[2][4];
#pragma unroll
    for (int mi = 0; mi < 2; ++mi)
#pragma unroll
        for (int nj = 0; nj < 4; ++nj) { aR[mi][nj] = z4; aI[mi][nj] = z4; }

    for (int k0 = 0; k0 < H_; k0 += 64) {
        if (k0) __syncthreads();
        {   // A: xre and xim tiles via global_load_lds (pre-swizzled source)
            size_t so = (size_t)(m0 + arow) * H_ + k0 + (acb >> 1);
            ushort_t* dr = Ars + tid * 8;
            ushort_t* di = Ais + tid * 8;
#pragma unroll
            for (int ch = 0; ch < 4; ++ch) {
                gl16(xre + so + (size_t)ch * 32 * H_, dr + ch * 2048);
                gl16(xim + so + (size_t)ch * 32 * H_, di + ch * 2048);
            }
        }
        {   // B: packed bf16 weights, aligned uint4
            char* pr_ = (char*)Brs + brow * 128;
            char* pi_ = (char*)Bis + brow * 128;
#pragma unroll
            for (int cc = 0; cc < 2; ++cc) {
                int cb = bq + cc * 16;
                *(uint4*)(pr_ + (cb ^ bsw)) =
                    *(const uint4*)(Wpr + (size_t)wrow * H_ + k0 + (cb >> 1));
                *(uint4*)(pi_ + (cb ^ bsw)) =
                    *(const uint4*)(Wpi + (size_t)wrow * H_ + k0 + (cb >> 1));
            }
        }
        __syncthreads();
#pragma unroll
        for (int ks = 0; ks < 2; ++ks) {
            int off = (ks * 64 + lk) ^ lsw;
            short8 x0 = *(const short8*)((const char*)Ars + (rb + lr) * 128 + off);
            short8 x1 = *(const short8*)((const char*)Ars + (rb + 16 + lr) * 128 + off);
            short8 y0 = *(const short8*)((const char*)Ais + (rb + lr) * 128 + off);
            short8 y1 = *(const short8*)((const char*)Ais + (rb + 16 + lr) * 128 + off);
#pragma unroll
            for (int nj = 0; nj < 4; ++nj) {
                short8 wr_ = *(const short8*)((const char*)Brs + (nj * 16 + lr) * 128 + off);
                short8 wi_ = *(const short8*)((const char*)Bis + (nj * 16 + lr) * 128 + off);
                short8 wn = negbf(wi_);
                aR[0][nj] = MFMA16(x0, wr_, aR[0][nj]);
                aR[0][nj] = MFMA16(y0, wn,  aR[0][nj]);
                aR[1][nj] = MFMA16(x1, wr_, aR[1][nj]);
                aR[1][nj] = MFMA16(y1, wn,  aR[1][nj]);
                aI[0][nj] = MFMA16(x0, wi_, aI[0][nj]);
                aI[0][nj] = MFMA16(y0, wr_, aI[0][nj]);
                aI[1][nj] = MFMA16(x1, wi_, aI[1][nj]);
                aI[1][nj] = MFMA16(y1, wr_, aI[1][nj]);
            }
        }
    }
    // ragged k=256 column inputs (one complex pair per output row)
    float xcr[8], xci[8];
#pragma unroll
    for (int mi = 0; mi < 2; ++mi)
#pragma unroll
        for (int r = 0; r < 4; ++r) {
            int row = m0 + rb + mi * 16 + ((l >> 4) << 2) + r;
            size_t pi = (size_t)row * DIN_ + 256;
            float re, im;
            if (f32) { float2 v = ((const float2*)x)[pi]; re = v.x; im = v.y; }
            else { uint_t v = ((const uint_t*)x)[pi];
                   re = bfu((ushort_t)(v & 0xFFFF)); im = bfu((ushort_t)(v >> 16)); }
            xcr[mi * 4 + r] = re; xci[mi * 4 + r] = im;
        }
#pragma unroll
    for (int nj = 0; nj < 4; ++nj) {
        int col = n0 + nj * 16 + lr;
        float wcr = ldi(eWr, (size_t)col * DIN_ + 256, f32);
        float wci = ldi(eWi, (size_t)col * DIN_ + 256, f32);
        float bR = ldi(br, col, f32), bI = ldi(bi, col, f32);
#pragma unroll
        for (int mi = 0; mi < 2; ++mi)
#pragma unroll
            for (int r = 0; r < 4; ++r) {
                int row = m0 + rb + mi * 16 + ((l >> 4) << 2) + r;
                int q = mi * 4 + r;
                float re = aR[mi][nj][r] + xcr[q] * wcr - xci[q] * wci + bR;
                float im = aI[mi][nj][r] + xcr[q] * wci + xci[q] * wcr + bI;
                size_t off = (size_t)row * H_ + col;
                xr[off]  = f2bf(re);
                xi_[off] = f2bf(im);
            }
    }
}

// ---------------- Pass A: per-chunk local state inject (states -> bf16) ---
// 2 threads per h, 16 states each as 8 packed f32x2 pairs (v_pk_fma_f32);
// 128-h slice per block (grid.z = 2); U tile (128x128, 32 KB) via gl16.
__global__ __launch_bounds__(256) void pass_a(
        const ushort_t* __restrict__ U, const float* __restrict__ P, ushort_t* __restrict__ S) {
    __shared__ __align__(16) ushort_t Us[Q_ * 128];  // 32 KB
    int c = blockIdx.x, b = blockIdx.y, z = blockIdx.z;
    int tid = threadIdx.x;
    int wv = tid >> 6, l = tid & 63;
    int hl = tid >> 1, h = z * 128 + hl;
    int nb = (tid & 1) * 16;
    const ushort_t* ub = U + (size_t)(b * L_ + c * Q_) * H_ + z * 128;
#pragma unroll
    for (int p = 0; p < 8; ++p) {
        int row = p * 16 + wv * 4 + (l >> 4);
        gl16(ub + (size_t)row * H_ + (l & 15) * 8,
             Us + (p * 16 + wv * 4) * 128 + l * 8);
    }
    f32x2 wr2[8], wi2[8], sr2[8], si2[8];
#pragma unroll
    for (int i = 0; i < 8; ++i) {
        int o0 = (nb + 2 * i) * H_ + h;
        wr2[i] = f32x2{P[o0], P[o0 + H_]};
        wi2[i] = f32x2{P[NH_ + o0], P[NH_ + o0 + H_]};
        sr2[i] = f32x2{0.f, 0.f}; si2[i] = f32x2{0.f, 0.f};
    }
    __syncthreads();
    float uvn = bfu(Us[hl]);
    for (int t = 0; t < Q_; ++t) {
        float uv = uvn;
        int tn = (t + 1 < Q_) ? t + 1 : t;
        uvn = bfu(Us[tn * 128 + hl]);
        f32x2 uvv = {uv, uv};
#pragma unroll
        for (int i = 0; i < 8; ++i) {
            f32x2 t1 = fma2(-wi2[i], si2[i], uvv);
            f32x2 nr = fma2(wr2[i], sr2[i], t1);
            f32x2 t2 = wi2[i] * sr2[i];
            si2[i] = fma2(wr2[i], si2[i], t2);
            sr2[i] = nr;
        }
    }
    size_t o = (size_t)(b * NC_ + c) * N_ * H_ + h;
#pragma unroll
    for (int i = 0; i < 8; ++i) {
        S[o + (nb + 2 * i) * H_]            = f2bf(sr2[i].x);
        S[o + (nb + 2 * i + 1) * H_]        = f2bf(sr2[i].y);
        S[o + (nb + 2 * i) * H_ + SSZ_]     = f2bf(si2[i].x);
        S[o + (nb + 2 * i + 1) * H_ + SSZ_] = f2bf(si2[i].y);
    }
}

// ---------------- Pass B: chunk-level carry scan (in-place -> init state) -
// 1-deep software prefetch: next chunk's loads issue before current store.
__global__ __launch_bounds__(256) void pass_b(
        const float* __restrict__ P, ushort_t* __restrict__ S) {
    int n = blockIdx.x, b = blockIdx.y, h = threadIdx.x;
    float wqr = P[4 * NH_ + n * H_ + h], wqi = P[5 * NH_ + n * H_ + h];
    float Xr = 0.f, Xi = 0.f;
    size_t idx = ((size_t)(b * NC_) * N_ + n) * H_ + h;
    float nlr = bfu(S[idx]), nli = bfu(S[idx + SSZ_]);
    for (int c = 0; c < NC_; ++c) {
        float lr = nlr, li = nli;
        if (c + 1 < NC_) {
            nlr = bfu(S[idx + NH_]);
            nli = bfu(S[idx + NH_ + SSZ_]);
        }
        S[idx] = f2bf(Xr); S[idx + SSZ_] = f2bf(Xi);   // init state for chunk c
        float nr = fmaf(wqr, Xr, fmaf(-wqi, Xi, lr));
        Xi = fmaf(wqr, Xi, fmaf(wqi, Xr, li));
        Xr = nr;
        idx += NH_;
    }
}

// ---------------- Pass C: scan w/ init + y=conv+D*u -> gelu --------------
// 2 threads per h, 16 states as 8 packed f32x2 pairs; 128-h slice (z = 2).
__global__ __launch_bounds__(256) void pass_c(
        const ushort_t* __restrict__ U, const float* __restrict__ P,
        const ushort_t* __restrict__ S, const void* __restrict__ Dp, int doff,
        ushort_t* __restrict__ G, const int* __restrict__ dfl) {
    __shared__ __align__(16) ushort_t Us[Q_ * 128];  // 32 KB
    int f32 = *dfl;
    int c = blockIdx.x, b = blockIdx.y, z = blockIdx.z;
    int tid = threadIdx.x;
    int wv = tid >> 6, l = tid & 63;
    int hl = tid >> 1, h = z * 128 + hl;
    int nb = (tid & 1) * 16;
    const ushort_t* ub = U + (size_t)(b * L_ + c * Q_) * H_ + z * 128;
#pragma unroll
    for (int p = 0; p < 8; ++p) {
        int row = p * 16 + wv * 4 + (l >> 4);
        gl16(ub + (size_t)row * H_ + (l & 15) * 8,
             Us + (p * 16 + wv * 4) * 128 + l * 8);
    }
    f32x2 wr2[8], wi2[8], cr2[8], ci2[8], sr2[8], si2[8];
#pragma unroll
    for (int i = 0; i < 8; ++i) {
        int o0 = (nb + 2 * i) * H_ + h;
        wr2[i] = f32x2{P[o0], P[o0 + H_]};
        wi2[i] = f32x2{P[NH_ + o0], P[NH_ + o0 + H_]};
        cr2[i] = f32x2{P[2 * NH_ + o0], P[2 * NH_ + o0 + H_]};
        ci2[i] = f32x2{P[3 * NH_ + o0], P[3 * NH_ + o0 + H_]};
    }
    size_t so = (size_t)(b * NC_ + c) * N_ * H_ + h;
#pragma unroll
    for (int i = 0; i < 8; ++i) {
        sr2[i] = f32x2{bfu(S[so + (nb + 2 * i) * H_]),
                       bfu(S[so + (nb + 2 * i + 1) * H_])};
        si2[i] = f32x2{bfu(S[so + (nb + 2 * i) * H_ + SSZ_]),
                       bfu(S[so + (nb + 2 * i + 1) * H_ + SSZ_])};
    }
    float Dv = ldi(Dp, (size_t)doff + h, f32);
    ushort_t* g = G + (size_t)(b * L_ + c * Q_) * H_ + h;
    __syncthreads();
    float uvn = bfu(Us[hl]);
    for (int t = 0; t < Q_; ++t) {
        float uv = uvn;
        int tn = (t + 1 < Q_) ? t + 1 : t;
        uvn = bfu(Us[tn * 128 + hl]);
        f32x2 uvv = {uv, uv};
        f32x2 a2 = {0.f, 0.f};
#pragma unroll
        for (int i = 0; i < 8; ++i) {
            f32x2 t1 = fma2(-wi2[i], si2[i], uvv);
            f32x2 nr = fma2(wr2[i], sr2[i], t1);
            f32x2 t2 = wi2[i] * sr2[i];
            si2[i] = fma2(wr2[i], si2[i], t2);
            sr2[i] = nr;
            a2 = fma2(cr2[i], nr, a2);
            a2 = fma2(-ci2[i], si2[i], a2);
        }
        float acc = a2.x + a2.y;
        acc += __shfl_xor(acc, 1, 64);           // combine the two 16-state halves
        float y = fmaf(Dv, uv, acc);
        float ge = 0.5f * y * (1.0f + erff(y * 0.70710678118654752f));
        if ((tid & 1) == 0) g[(size_t)t * H_] = f2bf(ge);
    }
}

// ---------------- Wout GEMM (MFMA) + bias + GLU, accumulate into z -------
// mode: 0 = store, 1 = add, 2 = sub
__global__ __launch_bounds__(256) void wout_gemm(
        const ushort_t* __restrict__ Gb, const void* __restrict__ W, size_t woff,
        const void* __restrict__ bo, int boff, ushort_t* __restrict__ Z, int mode,
        const int* __restrict__ dfl) {
    __shared__ __align__(16) ushort_t As[8192];   // 128 x 64 bf16 (swizzled)
    __shared__ __align__(16) ushort_t Bs[8192];   // 128 x 64 bf16 (swizzled)
    int f32 = *dfl;
    int m0 = blockIdx.x * 128, n0 = blockIdx.y * 64;
    int tid = threadIdx.x;
    int w = tid >> 6, l = tid & 63;
    int rb = w * 32;                              // wave's 32-row slice
    int lr = l & 15, lk = (l >> 4) << 4;          // frag row-in-16 / k-octet byte
    int lsw = (l & 7) << 4;                       // read-side swizzle
    int arow = tid >> 3;                          // 0..31 (+ch*32)
    int acb  = ((tid & 7) << 4) ^ ((arow & 7) << 4);  // logical colbyte at dest slot
    int brow = tid >> 1;                          // 0..127
    int bhalf = (tid & 1) << 6;                   // colbyte 0 or 64
    int bsw = (brow & 7) << 4;
    int wrow = (brow < 64) ? (n0 + brow) : (192 + n0 + brow);  // a rows / g rows
    f32x4 z4 = {0.f, 0.f, 0.f, 0.f};
    f32x4 acc[2][8];
#pragma unroll
    for (int mi = 0; mi < 2; ++mi)
#pragma unroll
        for (int nj = 0; nj < 8; ++nj) acc[mi][nj] = z4;

    for (int k0 = 0; k0 < H_; k0 += 64) {
        if (k0) __syncthreads();
        {   // A: 128x64 bf16, 4 chunks of 256 lanes x 16B
            const ushort_t* src = Gb + (size_t)(m0 + arow) * H_ + k0 + (acb >> 1);
            ushort_t* dst = As + tid * 8;
#pragma unroll
            for (int ch = 0; ch < 4; ++ch)
                gl16(src + (size_t)ch * 32 * H_, dst + ch * 2048);
        }
        {   // B: W rows -> swizzled LDS (64B per thread)
            size_t wb = woff + (size_t)wrow * H_ + k0;
            char* bp = (char*)Bs + brow * 128;
#pragma unroll
            for (int cc = 0; cc < 4; ++cc) {
                int cb = bhalf + cc * 16;
                uint4 v = ld8bf(W, wb + (cb >> 1), f32);
                *(uint4*)(bp + (cb ^ bsw)) = v;
            }
        }
        __syncthreads();
#pragma unroll
        for (int ks = 0; ks < 2; ++ks) {
            int off = (ks * 64 + lk) ^ lsw;
            short8 a0 = *(const short8*)((const char*)As + (rb + lr) * 128 + off);
            short8 a1 = *(const short8*)((const char*)As + (rb + 16 + lr) * 128 + off);
#pragma unroll
            for (int nj = 0; nj < 8; ++nj) {
                short8 bv = *(const short8*)((const char*)Bs + (nj * 16 + lr) * 128 + off);
                acc[0][nj] = MFMA16(a0, bv, acc[0][nj]);
                acc[1][nj] = MFMA16(a1, bv, acc[1][nj]);
            }
        }
    }
    float ba[4], bg[4];
#pragma unroll
    for (int nj = 0; nj < 4; ++nj) {
        ba[nj] = ldi(bo, (size_t)boff + n0 + nj * 16 + lr, f32);
        bg[nj] = ldi(bo, (size_t)boff + 256 + n0 + nj * 16 + lr, f32);
    }
#pragma unroll
    for (int mi = 0; mi < 2; ++mi)
#pragma unroll
        for (int nj = 0; nj < 4; ++nj)
#pragma unroll
            for (int r = 0; r < 4; ++r) {
                float av = acc[mi][nj][r] + ba[nj];
                float gv = acc[mi][nj + 4][r] + bg[nj];
                float s = av * (1.0f / (1.0f + expf(-gv)));
                int row = m0 + rb + mi * 16 + ((l >> 4) << 2) + r;
                size_t zo = (size_t)row * H_ + n0 + nj * 16 + lr;
                if (mode == 0)      Z[zo] = f2bf(s);
                else if (mode == 1) Z[zo] = f2bf(bfu(Z[zo]) + s);
                else                Z[zo] = f2bf(bfu(Z[zo]) - s);
            }
}

// ---------------- residual + LayerNorm: one wave per row -----------------
__global__ __launch_bounds__(256) void combine_ln(
        ushort_t* __restrict__ xr, ushort_t* __restrict__ xi,
        const ushort_t* __restrict__ zr, const ushort_t* __restrict__ zi,
        const void* __restrict__ gamma, const void* __restrict__ beta, int layer,
        const int* __restrict__ dfl) {
    int f32 = *dfl;
    int tid = threadIdx.x;
    int wv = tid >> 6, l = tid & 63;
    size_t row = (size_t)blockIdx.x * 4 + wv;
    size_t base = row * H_ + l * 4;
    uint2 vr2 = *(const uint2*)(xr + base);
    uint2 vi2 = *(const uint2*)(xi + base);
    uint2 zr2 = *(const uint2*)(zr + base);
    uint2 zi2 = *(const uint2*)(zi + base);
    float vr[4], vi[4];
    vr[0] = bfu((ushort_t)(vr2.x & 0xFFFF)) + bfu((ushort_t)(zr2.x & 0xFFFF));
    vr[1] = bfu((ushort_t)(vr2.x >> 16))    + bfu((ushort_t)(zr2.x >> 16));
    vr[2] = bfu((ushort_t)(vr2.y & 0xFFFF)) + bfu((ushort_t)(zr2.y & 0xFFFF));
    vr[3] = bfu((ushort_t)(vr2.y >> 16))    + bfu((ushort_t)(zr2.y >> 16));
    vi[0] = bfu((ushort_t)(vi2.x & 0xFFFF)) + bfu((ushort_t)(zi2.x & 0xFFFF));
    vi[1] = bfu((ushort_t)(vi2.x >> 16))    + bfu((ushort_t)(zi2.x >> 16));
    vi[2] = bfu((ushort_t)(vi2.y & 0xFFFF)) + bfu((ushort_t)(zi2.y & 0xFFFF));
    vi[3] = bfu((ushort_t)(vi2.y >> 16))    + bfu((ushort_t)(zi2.y >> 16));
    float s0 = 0.f, s1 = 0.f, s2 = 0.f, s3 = 0.f;
#pragma unroll
    for (int j = 0; j < 4; ++j) {
        s0 += vr[j]; s1 += vr[j] * vr[j];
        s2 += vi[j]; s3 += vi[j] * vi[j];
    }
#pragma unroll
    for (int off = 32; off >= 1; off >>= 1) {
        s0 += __shfl_xor(s0, off, 64); s1 += __shfl_xor(s1, off, 64);
        s2 += __shfl_xor(s2, off, 64); s3 += __shfl_xor(s3, off, 64);
    }
    const float invH = 1.0f / 256.0f;
    float mur = s0 * invH, varr = s1 * invH - mur * mur;
    float mui = s2 * invH, vari = s3 * invH - mui * mui;
    float rsr = rsqrtf(varr + 1e-5f), rsi = rsqrtf(vari + 1e-5f);
    float orv[4], oiv[4];
#pragma unroll
    for (int j = 0; j < 4; ++j) {
        int hh = l * 4 + j;
        float gr  = ldi(gamma, (size_t)(layer * 2 + 0) * H_ + hh, f32);
        float br_ = ldi(beta,  (size_t)(layer * 2 + 0) * H_ + hh, f32);
        float gi  = ldi(gamma, (size_t)(layer * 2 + 1) * H_ + hh, f32);
        float bi_ = ldi(beta,  (size_t)(layer * 2 + 1) * H_ + hh, f32);
        orv[j] = (vr[j] - mur) * rsr * gr + br_;
        oiv[j] = (vi[j] - mui) * rsi * gi + bi_;
    }
    *(uint2*)(xr + base) = pack4(orv[0], orv[1], orv[2], orv[3]);
    *(uint2*)(xi + base) = pack4(oiv[0], oiv[1], oiv[2], oiv[3]);
}

// ---------------- Decoder: complex GEMM (MFMA) (BL x 256) -> 257 ---------
__global__ __launch_bounds__(256) void dec_gemm(
        const ushort_t* __restrict__ xr, const ushort_t* __restrict__ xi,
        const void* __restrict__ Wr, const void* __restrict__ Wi,
        const void* __restrict__ br, const void* __restrict__ bi,
        void* __restrict__ out, const int* __restrict__ dfl) {
    __shared__ __align__(16) ushort_t Ars[8192];  // xr tile 128x64
    __shared__ __align__(16) ushort_t Ais[8192];  // xi tile 128x64
    __shared__ __align__(16) ushort_t Brs[4096];  // Wr tile  64x64
    __shared__ __align__(16) ushort_t Bis[4096];  // Wi tile  64x64
    int f32 = *dfl;
    int m0 = blockIdx.x * 128, n0 = blockIdx.y * 64;
    int tid = threadIdx.x;
    int w = tid >> 6, l = tid & 63;
    int rb = w * 32;
    int lr = l & 15, lk = (l >> 4) << 4, lsw = (l & 7) << 4;
    int arow = tid >> 3;
    int acb  = ((tid & 7) << 4) ^ ((arow & 7) << 4);
    int brow = tid >> 2;                          // 0..63
    int bq   = (tid & 3) << 5;                    // colbyte 0/32/64/96
    int bsw  = (brow & 7) << 4;
    int wrow = n0 + brow;
    bool bvalid = wrow < DOUT_;
    uint4 zz; zz.x = zz.y = zz.z = zz.w = 0u;
    f32x4 z4 = {0.f, 0.f, 0.f, 0.f};
    f32x4 aR[2][4], aI[2][4];
#pragma unroll
    for (int mi = 0; mi < 2; ++mi)
#pragma unroll
        for (int nj = 0; nj < 4; ++nj) { aR[mi][nj] = z4; aI[mi][nj] = z4; }

    for (int k0 = 0; k0 < H_; k0 += 64) {
        if (k0) __syncthreads();
        {   // A: xr and xi tiles via global_load_lds (pre-swizzled source)
            size_t so = (size_t)(m0 + arow) * H_ + k0 + (acb >> 1);
            ushort_t* dr = Ars + tid * 8;
            ushort_t* di = Ais + tid * 8;
#pragma unroll
            for (int ch = 0; ch < 4; ++ch) {
                gl16(xr + so + (size_t)ch * 32 * H_, dr + ch * 2048);
                gl16(xi + so + (size_t)ch * 32 * H_, di + ch * 2048);
            }
        }
        {   // B: Wr/Wi rows -> swizzled LDS, zero-fill past row 256
            size_t wb = (size_t)wrow * H_ + k0 + (bq >> 1);
            char* pr_ = (char*)Brs + brow * 128;
            char* pi_ = (char*)Bis + brow * 128;
#pragma unroll
            for (int cc = 0; cc < 2; ++cc) {
                int cb = bq + cc * 16;
                uint4 vr = zz, vi = zz;
                if (bvalid) {
                    vr = ld8bf(Wr, wb + cc * 8, f32);
                    vi = ld8bf(Wi, wb + cc * 8, f32);
                }
                *(uint4*)(pr_ + (cb ^ bsw)) = vr;
                *(uint4*)(pi_ + (cb ^ bsw)) = vi;
            }
        }
        __syncthreads();
#pragma unroll
        for (int ks = 0; ks < 2; ++ks) {
            int off = (ks * 64 + lk) ^ lsw;
            short8 x0 = *(const short8*)((const char*)Ars + (rb + lr) * 128 + off);
            short8 x1 = *(const short8*)((const char*)Ars + (rb + 16 + lr) * 128 + off);
            short8 y0 = *(const short8*)((const char*)Ais + (rb + lr) * 128 + off);
            short8 y1 = *(const short8*)((const char*)Ais + (rb + 16 + lr) * 128 + off);
#pragma unroll
            for (int nj = 0; nj < 4; ++nj) {
                short8 wr_ = *(const short8*)((const char*)Brs + (nj * 16 + lr) * 128 + off);
                short8 wi_ = *(const short8*)((const char*)Bis + (nj * 16 + lr) * 128 + off);
                short8 wn = negbf(wi_);
                aR[0][nj] = MFMA16(x0, wr_, aR[0][nj]);
                aR[0][nj] = MFMA16(y0, wn,  aR[0][nj]);
                aR[1][nj] = MFMA16(x1, wr_, aR[1][nj]);
                aR[1][nj] = MFMA16(y1, wn,  aR[1][nj]);
                aI[0][nj] = MFMA16(x0, wi_, aI[0][nj]);
                aI[0][nj] = MFMA16(y0, wr_, aI[0][nj]);
                aI[1][nj] = MFMA16(x1, wi_, aI[1][nj]);
                aI[1][nj] = MFMA16(y1, wr_, aI[1][nj]);
            }
        }
    }
#pragma unroll
    for (int nj = 0; nj < 4; ++nj) {
        int col = n0 + nj * 16 + lr;
        if (col < DOUT_) {
            float bR = ldi(br, col, f32), bI = ldi(bi, col, f32);
#pragma unroll
            for (int mi = 0; mi < 2; ++mi)
#pragma unroll
                for (int r = 0; r < 4; ++r) {
                    int row = m0 + rb + mi * 16 + ((l >> 4) << 2) + r;
                    size_t pi = (size_t)row * DOUT_ + col;
                    float re = aR[mi][nj][r] + bR;
                    float im = aI[mi][nj][r] + bI;
                    if (f32) {
                        ((float2*)out)[pi] = make_float2(re, im);
                    } else {
                        ((uint_t*)out)[pi] = (uint_t)f2bf(re) | ((uint_t)f2bf(im) << 16);
                    }
                }
        }
    }
}

// -------------------------------------------------------------------------
extern "C" void kernel_launch(void* const* d_in, const int* in_sizes, int n_in,
                              void* d_out, int out_size, void* d_ws, size_t ws_size,
                              hipStream_t stream) {
    const void* x      = d_in[0];
    const void* enc_Wr = d_in[1];
    const void* enc_Wi = d_in[2];
    const void* enc_br = d_in[3];
    const void* enc_bi = d_in[4];
    const void* log_dt = d_in[5];
    const void* lAr    = d_in[6];
    const void* Aim    = d_in[7];
    const void* C2     = d_in[8];
    const void* Dp     = d_in[9];
    const void* Wout   = d_in[10];
    const void* bout   = d_in[11];
    const void* gamma  = d_in[12];
    const void* beta   = d_in[13];
    const void* dec_Wr = d_in[14];
    const void* dec_Wi = d_in[15];
    const void* dec_br = d_in[16];
    const void* dec_bi = d_in[17];

    ushort_t* xr = (ushort_t*)d_ws;
    ushort_t* xi = xr + (size_t)PLANE_;
    ushort_t* gb = xi + (size_t)PLANE_;
    ushort_t* st = gb + (size_t)PLANE_;
    int*      fl = (int*)(st + (size_t)2 * SSZ_);
    float*    pr = (float*)(fl + 64);            // 256-byte pad for alignment
    ushort_t* zr = (ushort_t*)d_out;
    ushort_t* zi = zr + (size_t)PLANE_;
    ushort_t* xre = zr;                          // repacked x planes (pre-loop)
    ushort_t* xim = zi;
    ushort_t* Wpr = st;                          // packed enc weights (pre-loop)
    ushort_t* Wpi = st + 65536;

    probe_kernel<<<1, 256, 0, stream>>>(x, fl);
    param_kernel<<<256, 256, 0, stream>>>(log_dt, lAr, Aim, C2, pr, fl);
    repack_x<<<16384, 256, 0, stream>>>(x, xre, xim, fl);
    pack_encw<<<256, 256, 0, stream>>>(enc_Wr, enc_Wi, Wpr, Wpi, fl);
    enc_gemm<<<dim3(BL_ / 128, H_ / 64), 256, 0, stream>>>(xre, xim, Wpr, Wpi,
            x, enc_Wr, enc_Wi, enc_br, enc_bi, xr, xi, fl);

    for (int l = 0; l < NL_; ++l) {
        // zr = sr(xr) - si(xi);  zi = sr(xi) + si(xr)
        struct App { int br; const ushort_t* U; ushort_t* Zt; int mode; };
        App apps[4] = {
            {0, xr, zr, 0},   // sr(xr) -> zr (store)
            {1, xi, zr, 2},   // si(xi) -> zr (sub)
            {0, xi, zi, 0},   // sr(xi) -> zi (store)
            {1, xr, zi, 1},   // si(xr) -> zi (add)
        };
        for (int a = 0; a < 4; ++a) {
            const float* P = pr + (size_t)(l * 2 + apps[a].br) * 6 * NH_;
            pass_a<<<dim3(NC_, B_, 2), 256, 0, stream>>>(apps[a].U, P, st);
            pass_b<<<dim3(N_, B_), 256, 0, stream>>>(P, st);
            pass_c<<<dim3(NC_, B_, 2), 256, 0, stream>>>(apps[a].U, P, st,
                    Dp, (l * 2 + apps[a].br) * H_, gb, fl);
            wout_gemm<<<dim3(BL_ / 128, H_ / 64), 256, 0, stream>>>(gb,
                    Wout, (size_t)(l * 2 + apps[a].br) * 512 * H_,
                    bout, (l * 2 + apps[a].br) * 512,
                    apps[a].Zt, apps[a].mode, fl);
        }
        combine_ln<<<BL_ / 4, 256, 0, stream>>>(xr, xi, zr, zi, gamma, beta, l, fl);
    }

    dec_gemm<<<dim3(BL_ / 128, (DOUT_ + 63) / 64), 256, 0, stream>>>(
            xr, xi, dec_Wr, dec_Wi, dec_br, dec_bi, d_out, fl);
}